// Round 6
// baseline (335.969 us; speedup 1.0000x reference)
//
#include <hip/hip_runtime.h>
#include <stdint.h>

// B=2, CIN=256, COUT=256, H=W=128, K=3, G=4
#define HW    16384
#define CIN   256
#define COUT  256
#define Hh    128
#define Ww    128
#define OFFC  72        // G*2*K*K

typedef __attribute__((ext_vector_type(4))) float    f32x4;
typedef __attribute__((ext_vector_type(2))) _Float16 f16x2;
typedef __attribute__((ext_vector_type(8))) _Float16 f16x8;
typedef unsigned short u16;
typedef unsigned int   u32;

__device__ __forceinline__ u16 f2h(float f) { return __builtin_bit_cast(u16, (_Float16)f); }
__device__ __forceinline__ u32 pk2(float f) { u32 h = f2h(f); return h | (h << 16); }
__device__ __forceinline__ f16x2 bch(u32 u) { return __builtin_bit_cast(f16x2, u); }

// ---------------------------------------------------------------------------
// KPREP: {x f32 NCHW -> xt f16 [b*4+g][px][64]} + {w_deform -> wfrag f16
// [kc72][nt16][lane64][j8]} + {w_offset -> wfrag2 f16}. 18 KB LDS, f32x4 reads.
// ---------------------------------------------------------------------------
__global__ __launch_bounds__(256) void kprep(const float* __restrict__ x, const float* __restrict__ wd,
                                             const float* __restrict__ wo, u16* __restrict__ xt,
                                             u16* __restrict__ wfrag, u16* __restrict__ wfrag2) {
  __shared__ float smem[4608];                  // 18 KB
  int blk = blockIdx.x;
  if (blk < 2048) {                             // ---- transpose to NHWC f16 ----
    int bg = blk >> 8;
    int p0 = (blk & 255) << 6;
    const float* src = x + (size_t)bg * 64 * HW + p0;
    #pragma unroll
    for (int r = 0; r < 4; ++r) {               // f32x4 loads: 1 KB/wave-instr
      int idx = (threadIdx.x + 256 * r) * 4;
      int c = idx >> 6, px = idx & 63;
      f32x4 v = *(const f32x4*)(src + (size_t)c * HW + px);
      smem[c * 65 + px + 0] = v[0];
      smem[c * 65 + px + 1] = v[1];
      smem[c * 65 + px + 2] = v[2];
      smem[c * 65 + px + 3] = v[3];
    }
    __syncthreads();
    int px = threadIdx.x >> 2, seg = threadIdx.x & 3;
    u32 w[8];
    #pragma unroll
    for (int k = 0; k < 8; ++k) {
      float lo = smem[(seg * 16 + 2 * k) * 65 + px];
      float hi = smem[(seg * 16 + 2 * k + 1) * 65 + px];
      w[k] = (u32)f2h(lo) | ((u32)f2h(hi) << 16);
    }
    u16* dst = xt + ((size_t)bg * HW + p0 + px) * 64 + seg * 16;
    *(uint4*)dst       = make_uint4(w[0], w[1], w[2], w[3]);
    *(uint4*)(dst + 8) = make_uint4(w[4], w[5], w[6], w[7]);
  } else if (blk < 2176) {                      // ---- w_deform prepack (8 couts) ----
    int bb = blk - 2048;                        // 0..127
    int nh = bb & 31;                           // couts [nh*8, nh*8+8)
    int g  = bb >> 5;
    const float* src = wd + (size_t)(nh * 8) * 2304 + (size_t)g * 64 * 9;
    #pragma unroll
    for (int r = 0; r < 18; ++r) {
      int idx = threadIdx.x + 256 * r;          // 0..4607
      int cl  = idx / 576;
      int rem = idx - cl * 576;
      smem[cl * 576 + rem] = src[(size_t)cl * 2304 + rem];
    }
    __syncthreads();
    int nt = nh >> 1, nb = (nh & 1) * 8;
    #pragma unroll
    for (int r = 0; r < 18; ++r) {
      int o  = threadIdx.x + 256 * r;           // 0..4607
      int j  = o & 7;
      int n8 = (o >> 3) & 7;
      int q  = (o >> 6) & 3;
      int kcl = o >> 8;                         // t*2+half
      int t = kcl >> 1, half = kcl & 1;
      int cg = half * 32 + q * 8 + j;
      float v = smem[n8 * 576 + cg * 9 + t];
      int kc = (g * 9 + t) * 2 + half;
      int lane = q * 16 + nb + n8;
      wfrag[((size_t)(kc * 16 + nt) * 64 + lane) * 8 + j] = f2h(v);
    }
  } else {                                      // ---- w_offset prepack ----
    int e = (blk - 2176) * 256 + threadIdx.x;   // < 20480
    int j = e & 7;
    int lane = (e >> 3) & 63;
    int idx = e >> 9;
    int kc = idx / 5, nt = idx - 5 * kc;
    int n16 = lane & 15, q = lane >> 4;
    int oc = nt * 16 + n16;
    int c  = kc * 32 + q * 8 + j;
    float v = (oc < OFFC) ? wo[(size_t)oc * CIN + c] : 0.f;
    wfrag2[e] = f2h(v);
  }
}

// ---------------------------------------------------------------------------
// K2: producer/consumer fused DCN. Block = 8 waves (512 thr), M=64 px, N=256.
//   Waves 0-3 PRODUCE: gather corners (2-gt-deep reg pipeline) + bilerp -> LDS.
//   Waves 4-7 CONSUME: phase-0 offset conv, then A from LDS x B (reg-prefetched)
//   -> 32 MFMA/gt. Double-buffered A-stage, ONE barrier per gt.
// ---------------------------------------------------------------------------
__device__ __forceinline__ void mkpre(float yy, float xx, int* ob, u32* wp) {
  float y0f = floorf(yy), x0f = floorf(xx);
  float fy = yy - y0f, fx = xx - x0f;
  int y0 = (int)y0f, x0 = (int)x0f;
  int y1 = y0 + 1, x1 = x0 + 1;
  float vy0 = (y0 >= 0 && y0 < Hh) ? 1.f : 0.f;
  float vy1 = (y1 >= 0 && y1 < Hh) ? 1.f : 0.f;
  float vx0 = (x0 >= 0 && x0 < Ww) ? 1.f : 0.f;
  float vx1 = (x1 >= 0 && x1 < Ww) ? 1.f : 0.f;
  wp[0] = pk2((1.f - fy) * (1.f - fx) * vy0 * vx0);   // zero-pad folded into weights
  wp[1] = pk2((1.f - fy) * fx * vy0 * vx1);
  wp[2] = pk2(fy * (1.f - fx) * vy1 * vx0);
  wp[3] = pk2(fy * fx * vy1 * vx1);
  int cy0 = min(max(y0, 0), Hh - 1), cy1 = min(max(y1, 0), Hh - 1);
  int cx0 = min(max(x0, 0), Ww - 1), cx1 = min(max(x1, 0), Ww - 1);
  ob[0] = (cy0 * Ww + cx0) << 7;                // byte offsets, 128 B pixel records
  ob[1] = (cy0 * Ww + cx1) << 7;
  ob[2] = (cy1 * Ww + cx0) << 7;
  ob[3] = (cy1 * Ww + cx1) << 7;
}

__device__ __forceinline__ uint4 bil16(const uint4* v, const u32* wp) {
  f16x2 W0 = bch(wp[0]), W1 = bch(wp[1]), W2 = bch(wp[2]), W3 = bch(wp[3]);
  uint4 r;
  { f16x2 s = bch(v[0].x) * W0 + bch(v[1].x) * W1 + bch(v[2].x) * W2 + bch(v[3].x) * W3; r.x = __builtin_bit_cast(u32, s); }
  { f16x2 s = bch(v[0].y) * W0 + bch(v[1].y) * W1 + bch(v[2].y) * W2 + bch(v[3].y) * W3; r.y = __builtin_bit_cast(u32, s); }
  { f16x2 s = bch(v[0].z) * W0 + bch(v[1].z) * W1 + bch(v[2].z) * W2 + bch(v[3].z) * W3; r.z = __builtin_bit_cast(u32, s); }
  { f16x2 s = bch(v[0].w) * W0 + bch(v[1].w) * W1 + bch(v[2].w) * W2 + bch(v[3].w) * W3; r.w = __builtin_bit_cast(u32, s); }
  return r;
}

__global__ __launch_bounds__(512, 4) void k2(const u16* __restrict__ xt, const u16* __restrict__ wfrag2,
                                             const float* __restrict__ bo, const u16* __restrict__ wfrag,
                                             float* __restrict__ out) {
  __shared__ u16   astage[2 * 8 * 512];         // double-buffered A: 16 KB
  __shared__ float offl[36 * 64 * 2];           // [gt][px][{dy,dx}] = 18 KB
  int tid  = threadIdx.x;
  int lane = tid & 63, n16 = lane & 15, q = (tid >> 4) & 3;
  int wv   = tid >> 6;                          // 0..7
  bool prod = wv < 4;
  int  sw   = wv & 3;                           // producer: px subtile; consumer: cout quarter
  int b  = blockIdx.x >> 8;
  int p0 = (blockIdx.x & 255) << 6;
  int h  = p0 >> 7, w0 = p0 & 127;
  const char* xtb = (const char*)xt + (size_t)b * 4 * HW * 128;
  float fh  = (float)h;
  float fxp = (float)(w0 + sw * 16 + n16);      // producer's pixel x
  int   chb = q * 16;

  f32x4 acc[4][4];
  uint4 bf[8];
  uint4 d[2][8];
  u32   wp[2][4];

  // ---- phase 0: consumers compute offset conv -> offl; prefetch B(0) ----
  if (!prod) {
    f32x4 oacc[5];
    #pragma unroll
    for (int nt = 0; nt < 5; ++nt) {
      int oc = nt * 16 + n16;
      float bv = (oc < OFFC) ? bo[oc] : 0.f;
      oacc[nt] = (f32x4){bv, bv, bv, bv};
    }
    #pragma unroll
    for (int kc = 0; kc < 8; ++kc) {
      int g = kc >> 1;
      f16x8 af = __builtin_bit_cast(f16x8, *(const uint4*)(xtb +
          ((size_t)(g * HW + p0 + sw * 16 + n16)) * 128 + (kc & 1) * 64 + chb));
      #pragma unroll
      for (int nt = 0; nt < 5; ++nt) {
        f16x8 bfo = __builtin_bit_cast(f16x8, *(const uint4*)(wfrag2 + (size_t)(((kc * 5 + nt) << 6) + lane) * 8));
        oacc[nt] = __builtin_amdgcn_mfma_f32_16x16x32_f16(af, bfo, oacc[nt], 0, 0, 0);
      }
    }
    #pragma unroll
    for (int nt = 0; nt < 5; ++nt) {
      int oc = nt * 16 + n16;
      if (oc < OFFC) {
        int gt = oc >> 1, comp = oc & 1;
        #pragma unroll
        for (int r = 0; r < 4; ++r)
          offl[(gt * 64 + sw * 16 + q * 4 + r) * 2 + comp] = oacc[nt][r];
      }
    }
    #pragma unroll
    for (int mt = 0; mt < 4; ++mt)
      #pragma unroll
      for (int j = 0; j < 4; ++j) acc[mt][j] = (f32x4){0.f, 0.f, 0.f, 0.f};
    #pragma unroll
    for (int hh = 0; hh < 2; ++hh)              // prefetch B for gt=0 (kc 0,1)
      #pragma unroll
      for (int j = 0; j < 4; ++j)
        bf[hh * 4 + j] = *(const uint4*)(wfrag + ((size_t)((hh * 16 + sw * 4 + j)) * 64 + lane) * 8);
  }
  __syncthreads();                              // offl ready

  auto issue = [&](int gt, uint4* dd, u32* wpp) {
    float2 o = *(const float2*)&offl[(gt * 64 + sw * 16 + n16) * 2];
    int g = (gt * 57) >> 9;                     // gt/9
    int t = gt - g * 9;
    int i = (t * 683) >> 11;                    // t/3
    int j = t - i * 3;
    int ob[4];
    mkpre(fh + (float)(i - 1) + o.x, fxp + (float)(j - 1) + o.y, ob, wpp);
    const char* xg = xtb + (size_t)g * HW * 128;
    #pragma unroll
    for (int c = 0; c < 4; ++c) {
      dd[c]     = *(const uint4*)(xg + ob[c] + chb);
      dd[4 + c] = *(const uint4*)(xg + ob[c] + chb + 64);
    }
  };
  auto produce = [&](int slot, const uint4* dd, const u32* wpp) {
    *(uint4*)&astage[(slot * 8 + sw * 2 + 0) * 512 + lane * 8] = bil16(dd,     wpp);
    *(uint4*)&astage[(slot * 8 + sw * 2 + 1) * 512 + lane * 8] = bil16(dd + 4, wpp);
  };

  // ---- pipeline prologue: producers fill buf0, issue gt=1 ----
  if (prod) {
    issue(0, d[0], wp[0]);
    issue(1, d[1], wp[1]);
    produce(0, d[0], wp[0]);
  }
  __syncthreads();                              // buf0 ready

  // ---- main loop: one barrier per gt ----
  #pragma unroll 1
  for (int gt = 0; gt < 36; ++gt) {
    if (prod) {
      if (gt < 35) {
        int s = (gt + 1) & 1;
        produce(s, d[s], wp[s]);                // bilerp gt+1 -> other buffer
        if (gt + 2 < 36) issue(gt + 2, d[gt & 1], wp[gt & 1]);
      }
    } else {
      int slot = gt & 1;
      #pragma unroll
      for (int hh = 0; hh < 2; ++hh) {
        f16x8 af[4];
        #pragma unroll
        for (int mt = 0; mt < 4; ++mt)
          af[mt] = __builtin_bit_cast(f16x8,
              *(const uint4*)&astage[(slot * 8 + mt * 2 + hh) * 512 + lane * 8]);
        #pragma unroll
        for (int mt = 0; mt < 4; ++mt)
          #pragma unroll
          for (int j = 0; j < 4; ++j)
            acc[mt][j] = __builtin_amdgcn_mfma_f32_16x16x32_f16(
                af[mt], __builtin_bit_cast(f16x8, bf[hh * 4 + j]), acc[mt][j], 0, 0, 0);
      }
      if (gt < 35) {                            // prefetch B(gt+1)
        const u16* wb = wfrag + (size_t)(2 * (gt + 1) * 16 + sw * 4) * 512 + (size_t)lane * 8;
        #pragma unroll
        for (int hh = 0; hh < 2; ++hh)
          #pragma unroll
          for (int j = 0; j < 4; ++j)
            bf[hh * 4 + j] = *(const uint4*)(wb + (size_t)(hh * 16 + j) * 512);
      }
    }
    __syncthreads();
  }

  // ---- epilogue (consumers): px = p0+mt*16+q*4+r, cout = sw*64+j*16+n16 ----
  if (!prod) {
    float* op = out + (size_t)b * COUT * HW + p0;
    #pragma unroll
    for (int mt = 0; mt < 4; ++mt)
      #pragma unroll
      for (int j = 0; j < 4; ++j) {
        f32x4 v = acc[mt][j];
        #pragma unroll
        for (int r = 0; r < 4; ++r) v[r] = fmaxf(v[r], 0.f);
        int cout = sw * 64 + j * 16 + n16;
        *(f32x4*)(op + (size_t)cout * HW + mt * 16 + q * 4) = v;
      }
  }
}

// ---------------------------------------------------------------------------
extern "C" void kernel_launch(void* const* d_in, const int* in_sizes, int n_in,
                              void* d_out, int out_size, void* d_ws, size_t ws_size,
                              hipStream_t stream) {
  const float* x  = (const float*)d_in[0];
  const float* wo = (const float*)d_in[1];
  const float* bo = (const float*)d_in[2];
  const float* wd = (const float*)d_in[3];
  float* out = (float*)d_out;

  // ws: xt 16,777,216 | wfrag 1,179,648 | wfrag2 40,960
  u16* xtp    = (u16*)d_ws;
  u16* wfrag  = (u16*)((char*)d_ws + 16777216);
  u16* wfrag2 = (u16*)((char*)d_ws + 16777216 + 1179648);

  kprep<<<2256, 256, 0, stream>>>(x, wd, wo, xtp, wfrag, wfrag2);
  k2   <<<512,  512, 0, stream>>>(xtp, wfrag2, bo, wfrag, out);
}

// Round 7
// 309.817 us; speedup vs baseline: 1.0844x; 1.0844x over previous
//
#include <hip/hip_runtime.h>
#include <stdint.h>

// B=2, CIN=256, COUT=256, H=W=128, K=3, G=4
#define HW    16384
#define CIN   256
#define COUT  256
#define Hh    128
#define Ww    128
#define OFFC  72        // G*2*K*K

typedef __attribute__((ext_vector_type(4))) float    f32x4;
typedef __attribute__((ext_vector_type(2))) _Float16 f16x2;
typedef __attribute__((ext_vector_type(8))) _Float16 f16x8;
typedef unsigned short u16;
typedef unsigned int   u32;

__device__ __forceinline__ u16 f2h(float f) { return __builtin_bit_cast(u16, (_Float16)f); }
__device__ __forceinline__ u32 pk2(float f) { u32 h = f2h(f); return h | (h << 16); }
__device__ __forceinline__ f16x2 bch(u32 u) { return __builtin_bit_cast(f16x2, u); }

// ---------------------------------------------------------------------------
// KPREP: {x f32 NCHW -> xt f16 [b*4+g][px][64]} + {w_deform -> wfrag f16
// [kc72][nt16][lane64][j8]} + {w_offset -> wfrag2 f16}. 18 KB LDS, f32x4 reads.
// ---------------------------------------------------------------------------
__global__ __launch_bounds__(256) void kprep(const float* __restrict__ x, const float* __restrict__ wd,
                                             const float* __restrict__ wo, u16* __restrict__ xt,
                                             u16* __restrict__ wfrag, u16* __restrict__ wfrag2) {
  __shared__ float smem[4608];                  // 18 KB
  int blk = blockIdx.x;
  if (blk < 2048) {                             // ---- transpose to NHWC f16 ----
    int bg = blk >> 8;
    int p0 = (blk & 255) << 6;
    const float* src = x + (size_t)bg * 64 * HW + p0;
    #pragma unroll
    for (int r = 0; r < 4; ++r) {               // f32x4 loads: 1 KB/wave-instr
      int idx = (threadIdx.x + 256 * r) * 4;
      int c = idx >> 6, px = idx & 63;
      f32x4 v = *(const f32x4*)(src + (size_t)c * HW + px);
      smem[c * 65 + px + 0] = v[0];
      smem[c * 65 + px + 1] = v[1];
      smem[c * 65 + px + 2] = v[2];
      smem[c * 65 + px + 3] = v[3];
    }
    __syncthreads();
    int px = threadIdx.x >> 2, seg = threadIdx.x & 3;
    u32 w[8];
    #pragma unroll
    for (int k = 0; k < 8; ++k) {
      float lo = smem[(seg * 16 + 2 * k) * 65 + px];
      float hi = smem[(seg * 16 + 2 * k + 1) * 65 + px];
      w[k] = (u32)f2h(lo) | ((u32)f2h(hi) << 16);
    }
    u16* dst = xt + ((size_t)bg * HW + p0 + px) * 64 + seg * 16;
    *(uint4*)dst       = make_uint4(w[0], w[1], w[2], w[3]);
    *(uint4*)(dst + 8) = make_uint4(w[4], w[5], w[6], w[7]);
  } else if (blk < 2176) {                      // ---- w_deform prepack (8 couts) ----
    int bb = blk - 2048;                        // 0..127
    int nh = bb & 31;                           // couts [nh*8, nh*8+8)
    int g  = bb >> 5;
    const float* src = wd + (size_t)(nh * 8) * 2304 + (size_t)g * 64 * 9;
    #pragma unroll
    for (int r = 0; r < 18; ++r) {
      int idx = threadIdx.x + 256 * r;          // 0..4607
      int cl  = idx / 576;
      int rem = idx - cl * 576;
      smem[cl * 576 + rem] = src[(size_t)cl * 2304 + rem];
    }
    __syncthreads();
    int nt = nh >> 1, nb = (nh & 1) * 8;
    #pragma unroll
    for (int r = 0; r < 18; ++r) {
      int o  = threadIdx.x + 256 * r;           // 0..4607
      int j  = o & 7;
      int n8 = (o >> 3) & 7;
      int q  = (o >> 6) & 3;
      int kcl = o >> 8;                         // t*2+half
      int t = kcl >> 1, half = kcl & 1;
      int cg = half * 32 + q * 8 + j;
      float v = smem[n8 * 576 + cg * 9 + t];
      int kc = (g * 9 + t) * 2 + half;
      int lane = q * 16 + nb + n8;
      wfrag[((size_t)(kc * 16 + nt) * 64 + lane) * 8 + j] = f2h(v);
    }
  } else {                                      // ---- w_offset prepack ----
    int e = (blk - 2176) * 256 + threadIdx.x;   // < 20480
    int j = e & 7;
    int lane = (e >> 3) & 63;
    int idx = e >> 9;
    int kc = idx / 5, nt = idx - 5 * kc;
    int n16 = lane & 15, q = lane >> 4;
    int oc = nt * 16 + n16;
    int c  = kc * 32 + q * 8 + j;
    float v = (oc < OFFC) ? wo[(size_t)oc * CIN + c] : 0.f;
    wfrag2[e] = f2h(v);
  }
}

// ---------------------------------------------------------------------------
// K2: producer/consumer fused DCN. Block = 8 waves (512 thr), M=64 px, N=256.
//   Waves 0-3 PRODUCE: gather corners (2-gt-deep reg pipeline) + bilerp -> LDS.
//   Waves 4-7 CONSUME: phase-0 offset conv, then A from LDS x B -> 32 MFMA/gt.
//   Double-buffered A-stage, ONE barrier per gt.
//   __launch_bounds__(512,2): 2 blocks/CU -> 128-VGPR cap (R6's ",4" forced
//   64 VGPR -> 660 MB scratch spill; second arg is min BLOCKS per CU).
// ---------------------------------------------------------------------------
__device__ __forceinline__ void mkpre(float yy, float xx, int* ob, u32* wp) {
  float y0f = floorf(yy), x0f = floorf(xx);
  float fy = yy - y0f, fx = xx - x0f;
  int y0 = (int)y0f, x0 = (int)x0f;
  int y1 = y0 + 1, x1 = x0 + 1;
  float vy0 = (y0 >= 0 && y0 < Hh) ? 1.f : 0.f;
  float vy1 = (y1 >= 0 && y1 < Hh) ? 1.f : 0.f;
  float vx0 = (x0 >= 0 && x0 < Ww) ? 1.f : 0.f;
  float vx1 = (x1 >= 0 && x1 < Ww) ? 1.f : 0.f;
  wp[0] = pk2((1.f - fy) * (1.f - fx) * vy0 * vx0);   // zero-pad folded into weights
  wp[1] = pk2((1.f - fy) * fx * vy0 * vx1);
  wp[2] = pk2(fy * (1.f - fx) * vy1 * vx0);
  wp[3] = pk2(fy * fx * vy1 * vx1);
  int cy0 = min(max(y0, 0), Hh - 1), cy1 = min(max(y1, 0), Hh - 1);
  int cx0 = min(max(x0, 0), Ww - 1), cx1 = min(max(x1, 0), Ww - 1);
  ob[0] = (cy0 * Ww + cx0) << 7;                // byte offsets, 128 B pixel records
  ob[1] = (cy0 * Ww + cx1) << 7;
  ob[2] = (cy1 * Ww + cx0) << 7;
  ob[3] = (cy1 * Ww + cx1) << 7;
}

__device__ __forceinline__ uint4 bil16(const uint4* v, const u32* wp) {
  f16x2 W0 = bch(wp[0]), W1 = bch(wp[1]), W2 = bch(wp[2]), W3 = bch(wp[3]);
  uint4 r;
  { f16x2 s = bch(v[0].x) * W0 + bch(v[1].x) * W1 + bch(v[2].x) * W2 + bch(v[3].x) * W3; r.x = __builtin_bit_cast(u32, s); }
  { f16x2 s = bch(v[0].y) * W0 + bch(v[1].y) * W1 + bch(v[2].y) * W2 + bch(v[3].y) * W3; r.y = __builtin_bit_cast(u32, s); }
  { f16x2 s = bch(v[0].z) * W0 + bch(v[1].z) * W1 + bch(v[2].z) * W2 + bch(v[3].z) * W3; r.z = __builtin_bit_cast(u32, s); }
  { f16x2 s = bch(v[0].w) * W0 + bch(v[1].w) * W1 + bch(v[2].w) * W2 + bch(v[3].w) * W3; r.w = __builtin_bit_cast(u32, s); }
  return r;
}

__global__ __launch_bounds__(512, 2) void k2(const u16* __restrict__ xt, const u16* __restrict__ wfrag2,
                                             const float* __restrict__ bo, const u16* __restrict__ wfrag,
                                             float* __restrict__ out) {
  __shared__ u16   astage[2 * 8 * 512];         // double-buffered A: 16 KB
  __shared__ float offl[64 * 74];               // [px][oc] stride-74: conflict-safe, 18.5 KB
  int tid  = threadIdx.x;
  int lane = tid & 63, n16 = lane & 15, q = (tid >> 4) & 3;
  int wv   = tid >> 6;                          // 0..7
  bool prod = wv < 4;
  int  sw   = wv & 3;                           // producer: px subtile; consumer: cout quarter
  int b  = blockIdx.x >> 8;
  int p0 = (blockIdx.x & 255) << 6;
  int h  = p0 >> 7, w0 = p0 & 127;
  const char* xtb = (const char*)xt + (size_t)b * 4 * HW * 128;
  float fh  = (float)h;
  float fxp = (float)(w0 + sw * 16 + n16);      // producer's pixel x
  int   chb = q * 16;

  f32x4 acc[4][4];
  uint4 bf0[4];                                 // persistent: next hh=0 B-frags
  uint4 d[2][8];
  u32   wp[2][4];

  // ---- phase 0: consumers compute offset conv -> offl; prefetch B(0,hh=0) ----
  if (!prod) {
    f32x4 oacc[5];
    #pragma unroll
    for (int nt = 0; nt < 5; ++nt) {
      int oc = nt * 16 + n16;
      float bv = (oc < OFFC) ? bo[oc] : 0.f;
      oacc[nt] = (f32x4){bv, bv, bv, bv};
    }
    #pragma unroll
    for (int kc = 0; kc < 8; ++kc) {
      int g = kc >> 1;
      f16x8 af = __builtin_bit_cast(f16x8, *(const uint4*)(xtb +
          ((size_t)(g * HW + p0 + sw * 16 + n16)) * 128 + (kc & 1) * 64 + chb));
      #pragma unroll
      for (int nt = 0; nt < 5; ++nt) {
        f16x8 bfo = __builtin_bit_cast(f16x8, *(const uint4*)(wfrag2 + (size_t)(((kc * 5 + nt) << 6) + lane) * 8));
        oacc[nt] = __builtin_amdgcn_mfma_f32_16x16x32_f16(af, bfo, oacc[nt], 0, 0, 0);
      }
    }
    #pragma unroll
    for (int nt = 0; nt < 5; ++nt) {
      int oc = nt * 16 + n16;
      if (oc < OFFC) {
        #pragma unroll
        for (int r = 0; r < 4; ++r)
          offl[(sw * 16 + q * 4 + r) * 74 + oc] = oacc[nt][r];
      }
    }
    #pragma unroll
    for (int mt = 0; mt < 4; ++mt)
      #pragma unroll
      for (int j = 0; j < 4; ++j) acc[mt][j] = (f32x4){0.f, 0.f, 0.f, 0.f};
    #pragma unroll
    for (int j = 0; j < 4; ++j)                 // B(kc=0): hh=0 of gt=0
      bf0[j] = *(const uint4*)(wfrag + ((size_t)(sw * 4 + j) * 64 + lane) * 8);
  }
  __syncthreads();                              // offl ready

  auto issue = [&](int gt, uint4* dd, u32* wpp) {
    int pxl = sw * 16 + n16;
    float oy = offl[pxl * 74 + gt * 2];
    float ox = offl[pxl * 74 + gt * 2 + 1];
    int g = (gt * 57) >> 9;                     // gt/9
    int t = gt - g * 9;
    int i = (t * 683) >> 11;                    // t/3
    int j = t - i * 3;
    int ob[4];
    mkpre(fh + (float)(i - 1) + oy, fxp + (float)(j - 1) + ox, ob, wpp);
    const char* xg = xtb + (size_t)g * HW * 128;
    #pragma unroll
    for (int c = 0; c < 4; ++c) {
      dd[c]     = *(const uint4*)(xg + ob[c] + chb);
      dd[4 + c] = *(const uint4*)(xg + ob[c] + chb + 64);
    }
  };
  auto produce = [&](int slot, const uint4* dd, const u32* wpp) {
    *(uint4*)&astage[(slot * 8 + sw * 2 + 0) * 512 + lane * 8] = bil16(dd,     wpp);
    *(uint4*)&astage[(slot * 8 + sw * 2 + 1) * 512 + lane * 8] = bil16(dd + 4, wpp);
  };

  // ---- pipeline prologue: producers fill buf0, issue gt=1 ----
  if (prod) {
    issue(0, d[0], wp[0]);
    issue(1, d[1], wp[1]);
    produce(0, d[0], wp[0]);
  }
  __syncthreads();                              // buf0 ready

  // ---- main loop: one barrier per gt ----
  #pragma unroll 1
  for (int gt = 0; gt < 36; ++gt) {
    if (prod) {
      if (gt < 35) {
        int s = (gt + 1) & 1;
        produce(s, d[s], wp[s]);                // bilerp gt+1 -> other buffer
        if (gt + 2 < 36) issue(gt + 2, d[gt & 1], wp[gt & 1]);
      }
    } else {
      int slot = gt & 1;
      // transient hh=1 B-frags (wfrag is L1/L2-hot; hidden behind hh=0 MFMAs)
      uint4 bf1[4];
      const u16* wb1 = wfrag + ((size_t)((2 * gt + 1) * 16 + sw * 4) * 64 + lane) * 8;
      #pragma unroll
      for (int j = 0; j < 4; ++j) bf1[j] = *(const uint4*)(wb1 + (size_t)j * 512);
      f16x8 af0[4];
      #pragma unroll
      for (int mt = 0; mt < 4; ++mt)
        af0[mt] = __builtin_bit_cast(f16x8,
            *(const uint4*)&astage[(slot * 8 + mt * 2 + 0) * 512 + lane * 8]);
      #pragma unroll
      for (int mt = 0; mt < 4; ++mt)
        #pragma unroll
        for (int j = 0; j < 4; ++j)
          acc[mt][j] = __builtin_amdgcn_mfma_f32_16x16x32_f16(
              af0[mt], __builtin_bit_cast(f16x8, bf0[j]), acc[mt][j], 0, 0, 0);
      f16x8 af1[4];
      #pragma unroll
      for (int mt = 0; mt < 4; ++mt)
        af1[mt] = __builtin_bit_cast(f16x8,
            *(const uint4*)&astage[(slot * 8 + mt * 2 + 1) * 512 + lane * 8]);
      #pragma unroll
      for (int mt = 0; mt < 4; ++mt)
        #pragma unroll
        for (int j = 0; j < 4; ++j)
          acc[mt][j] = __builtin_amdgcn_mfma_f32_16x16x32_f16(
              af1[mt], __builtin_bit_cast(f16x8, bf1[j]), acc[mt][j], 0, 0, 0);
      if (gt < 35) {                            // prefetch hh=0 B of gt+1
        const u16* wb0 = wfrag + ((size_t)((2 * gt + 2) * 16 + sw * 4) * 64 + lane) * 8;
        #pragma unroll
        for (int j = 0; j < 4; ++j) bf0[j] = *(const uint4*)(wb0 + (size_t)j * 512);
      }
    }
    __syncthreads();
  }

  // ---- epilogue (consumers): px = p0+mt*16+q*4+r, cout = sw*64+j*16+n16 ----
  if (!prod) {
    float* op = out + (size_t)b * COUT * HW + p0;
    #pragma unroll
    for (int mt = 0; mt < 4; ++mt)
      #pragma unroll
      for (int j = 0; j < 4; ++j) {
        f32x4 v = acc[mt][j];
        #pragma unroll
        for (int r = 0; r < 4; ++r) v[r] = fmaxf(v[r], 0.f);
        int cout = sw * 64 + j * 16 + n16;
        *(f32x4*)(op + (size_t)cout * HW + mt * 16 + q * 4) = v;
      }
  }
}

// ---------------------------------------------------------------------------
extern "C" void kernel_launch(void* const* d_in, const int* in_sizes, int n_in,
                              void* d_out, int out_size, void* d_ws, size_t ws_size,
                              hipStream_t stream) {
  const float* x  = (const float*)d_in[0];
  const float* wo = (const float*)d_in[1];
  const float* bo = (const float*)d_in[2];
  const float* wd = (const float*)d_in[3];
  float* out = (float*)d_out;

  // ws: xt 16,777,216 | wfrag 1,179,648 | wfrag2 40,960
  u16* xtp    = (u16*)d_ws;
  u16* wfrag  = (u16*)((char*)d_ws + 16777216);
  u16* wfrag2 = (u16*)((char*)d_ws + 16777216 + 1179648);

  kprep<<<2256, 256, 0, stream>>>(x, wd, wo, xtp, wfrag, wfrag2);
  k2   <<<512,  512, 0, stream>>>(xtp, wfrag2, bo, wfrag, out);
}

// Round 8
// 303.214 us; speedup vs baseline: 1.1080x; 1.0218x over previous
//
#include <hip/hip_runtime.h>
#include <stdint.h>

// B=2, CIN=256, COUT=256, H=W=128, K=3, G=4
#define HW    16384
#define CIN   256
#define COUT  256
#define Hh    128
#define Ww    128
#define OFFC  72        // G*2*K*K

typedef __attribute__((ext_vector_type(4))) float    f32x4;
typedef __attribute__((ext_vector_type(2))) _Float16 f16x2;
typedef __attribute__((ext_vector_type(8))) _Float16 f16x8;
typedef unsigned short u16;
typedef unsigned int   u32;

__device__ __forceinline__ u16 f2h(float f) { return __builtin_bit_cast(u16, (_Float16)f); }
__device__ __forceinline__ u32 pk2(float f) { u32 h = f2h(f); return h | (h << 16); }
__device__ __forceinline__ f16x2 bch(u32 u) { return __builtin_bit_cast(f16x2, u); }

// ---------------------------------------------------------------------------
// KPREP: {x f32 NCHW -> xt f16 [b*4+g][px][64]} (128-px tiles) + {w_deform ->
// wfrag f16 [kc72][nt16][lane64][j8]} + {w_offset -> wfrag2 f16}
// ---------------------------------------------------------------------------
__global__ __launch_bounds__(256) void kprep(const float* __restrict__ x, const float* __restrict__ wd,
                                             const float* __restrict__ wo, u16* __restrict__ xt,
                                             u16* __restrict__ wfrag, u16* __restrict__ wfrag2) {
  __shared__ float smem[64 * 129];              // 33 KB
  int blk = blockIdx.x;
  if (blk < 1024) {                             // ---- transpose to NHWC f16, 128 px ----
    int bg = blk >> 7;
    int p0 = (blk & 127) << 7;
    const float* src = x + (size_t)bg * 64 * HW + p0;
    #pragma unroll
    for (int r = 0; r < 8; ++r) {
      int idx = (threadIdx.x + 256 * r) * 4;    // 0..8191
      int c = idx >> 7, px = idx & 127;
      f32x4 v = *(const f32x4*)(src + (size_t)c * HW + px);
      smem[c * 129 + px + 0] = v[0];
      smem[c * 129 + px + 1] = v[1];
      smem[c * 129 + px + 2] = v[2];
      smem[c * 129 + px + 3] = v[3];
    }
    __syncthreads();
    int px = threadIdx.x >> 1, seg = threadIdx.x & 1;   // seg = 32-ch half
    u32 w[16];
    #pragma unroll
    for (int k = 0; k < 16; ++k) {
      float lo = smem[(seg * 32 + 2 * k) * 129 + px];
      float hi = smem[(seg * 32 + 2 * k + 1) * 129 + px];
      w[k] = (u32)f2h(lo) | ((u32)f2h(hi) << 16);
    }
    u16* dst = xt + ((size_t)bg * HW + p0 + px) * 64 + seg * 32;
    *(uint4*)(dst + 0)  = make_uint4(w[0],  w[1],  w[2],  w[3]);
    *(uint4*)(dst + 8)  = make_uint4(w[4],  w[5],  w[6],  w[7]);
    *(uint4*)(dst + 16) = make_uint4(w[8],  w[9],  w[10], w[11]);
    *(uint4*)(dst + 24) = make_uint4(w[12], w[13], w[14], w[15]);
  } else if (blk < 1152) {                      // ---- w_deform prepack (8 couts) ----
    int bb = blk - 1024;                        // 0..127
    int nh = bb & 31;                           // couts [nh*8, nh*8+8)
    int g  = bb >> 5;
    const float* src = wd + (size_t)(nh * 8) * 2304 + (size_t)g * 64 * 9;
    #pragma unroll
    for (int r = 0; r < 18; ++r) {
      int idx = threadIdx.x + 256 * r;          // 0..4607
      int cl  = idx / 576;
      int rem = idx - cl * 576;
      smem[cl * 576 + rem] = src[(size_t)cl * 2304 + rem];
    }
    __syncthreads();
    int nt = nh >> 1, nb = (nh & 1) * 8;
    #pragma unroll
    for (int r = 0; r < 18; ++r) {
      int o  = threadIdx.x + 256 * r;           // 0..4607
      int j  = o & 7;
      int n8 = (o >> 3) & 7;
      int q  = (o >> 6) & 3;
      int kcl = o >> 8;                         // t*2+half
      int t = kcl >> 1, half = kcl & 1;
      int cg = half * 32 + q * 8 + j;
      float v = smem[n8 * 576 + cg * 9 + t];
      int kc = (g * 9 + t) * 2 + half;
      int lane = q * 16 + nb + n8;
      wfrag[((size_t)(kc * 16 + nt) * 64 + lane) * 8 + j] = f2h(v);
    }
  } else {                                      // ---- w_offset prepack ----
    int e = (blk - 1152) * 256 + threadIdx.x;   // < 20480
    int j = e & 7;
    int lane = (e >> 3) & 63;
    int idx = e >> 9;
    int kc = idx / 5, nt = idx - 5 * kc;
    int n16 = lane & 15, q = lane >> 4;
    int oc = nt * 16 + n16;
    int c  = kc * 32 + q * 8 + j;
    float v = (oc < OFFC) ? wo[(size_t)oc * CIN + c] : 0.f;
    wfrag2[e] = f2h(v);
  }
}

// ---------------------------------------------------------------------------
// K2: symmetric fused DCN. Block = 8 waves (512 thr), M=64 px, N=256.
//   Wave w PRODUCES A half-tile (subtile w>>1, 32-ch half w&1): 4 corner
//   dwordx4 gathers (2-gt-deep reg pipeline d[2][4]) + pk-f16 bilerp -> LDS.
//   Wave w CONSUMES all 8 half-tiles x cout slice [w*32, w*32+32): acc[4][2]
//   = 32 AGPRs. Per-wave total ~100 regs -> fits 128 cap, no spill (R6/R7's
//   asymmetric consumer needed ~130 -> 600 MB/launch scratch spill).
//   One barrier per gt; B hh=0 prefetched cross-gt, hh=1 loaded in-iter.
// ---------------------------------------------------------------------------
__device__ __forceinline__ void mkpre(float yy, float xx, int* ob, u32* wp) {
  float y0f = floorf(yy), x0f = floorf(xx);
  float fy = yy - y0f, fx = xx - x0f;
  int y0 = (int)y0f, x0 = (int)x0f;
  int y1 = y0 + 1, x1 = x0 + 1;
  float vy0 = (y0 >= 0 && y0 < Hh) ? 1.f : 0.f;
  float vy1 = (y1 >= 0 && y1 < Hh) ? 1.f : 0.f;
  float vx0 = (x0 >= 0 && x0 < Ww) ? 1.f : 0.f;
  float vx1 = (x1 >= 0 && x1 < Ww) ? 1.f : 0.f;
  wp[0] = pk2((1.f - fy) * (1.f - fx) * vy0 * vx0);   // zero-pad folded into weights
  wp[1] = pk2((1.f - fy) * fx * vy0 * vx1);
  wp[2] = pk2(fy * (1.f - fx) * vy1 * vx0);
  wp[3] = pk2(fy * fx * vy1 * vx1);
  int cy0 = min(max(y0, 0), Hh - 1), cy1 = min(max(y1, 0), Hh - 1);
  int cx0 = min(max(x0, 0), Ww - 1), cx1 = min(max(x1, 0), Ww - 1);
  ob[0] = (cy0 * Ww + cx0) << 7;                // byte offsets, 128 B pixel records
  ob[1] = (cy0 * Ww + cx1) << 7;
  ob[2] = (cy1 * Ww + cx0) << 7;
  ob[3] = (cy1 * Ww + cx1) << 7;
}

__device__ __forceinline__ uint4 bil16(const uint4* v, const u32* wp) {
  f16x2 W0 = bch(wp[0]), W1 = bch(wp[1]), W2 = bch(wp[2]), W3 = bch(wp[3]);
  uint4 r;
  { f16x2 s = bch(v[0].x) * W0 + bch(v[1].x) * W1 + bch(v[2].x) * W2 + bch(v[3].x) * W3; r.x = __builtin_bit_cast(u32, s); }
  { f16x2 s = bch(v[0].y) * W0 + bch(v[1].y) * W1 + bch(v[2].y) * W2 + bch(v[3].y) * W3; r.y = __builtin_bit_cast(u32, s); }
  { f16x2 s = bch(v[0].z) * W0 + bch(v[1].z) * W1 + bch(v[2].z) * W2 + bch(v[3].z) * W3; r.z = __builtin_bit_cast(u32, s); }
  { f16x2 s = bch(v[0].w) * W0 + bch(v[1].w) * W1 + bch(v[2].w) * W2 + bch(v[3].w) * W3; r.w = __builtin_bit_cast(u32, s); }
  return r;
}

__global__ __launch_bounds__(512, 2) void k2(const u16* __restrict__ xt, const u16* __restrict__ wfrag2,
                                             const float* __restrict__ bo, const u16* __restrict__ wfrag,
                                             float* __restrict__ out) {
  __shared__ u16   astage[2 * 8 * 512];         // [buf][s4][h2][lane][8] = 16 KB
  __shared__ float offl[64 * 74];               // [px][oc] stride-74, 18.5 KB
  int tid  = threadIdx.x;
  int lane = tid & 63, n16 = lane & 15, q = (tid >> 4) & 3;
  int wv   = tid >> 6;                          // 0..7
  int sp   = wv >> 1;                           // produced px subtile
  int hp   = wv & 1;                            // produced 32-ch half
  int b  = blockIdx.x >> 8;
  int p0 = (blockIdx.x & 255) << 6;
  int h  = p0 >> 7, w0 = p0 & 127;
  const char* xtb = (const char*)xt + (size_t)b * 4 * HW * 128;
  float fh  = (float)h;
  float fxp = (float)(w0 + sp * 16 + n16);      // producer-pixel x
  int   chb = hp * 64 + q * 16;                 // byte offset within 128 B record

  f32x4 acc[4][2];
  #pragma unroll
  for (int mt = 0; mt < 4; ++mt) {
    acc[mt][0] = (f32x4){0.f, 0.f, 0.f, 0.f};
    acc[mt][1] = (f32x4){0.f, 0.f, 0.f, 0.f};
  }
  uint4 bf0[2];                                 // persistent hh=0 B-frags (slice wv)
  uint4 d[2][4];
  u32   wp[2][4];

  // ---- phase 0: waves 0-3 compute offset conv -> offl ----
  if (wv < 4) {
    f32x4 oacc[5];
    #pragma unroll
    for (int nt = 0; nt < 5; ++nt) {
      int oc = nt * 16 + n16;
      float bv = (oc < OFFC) ? bo[oc] : 0.f;
      oacc[nt] = (f32x4){bv, bv, bv, bv};
    }
    #pragma unroll
    for (int kc = 0; kc < 8; ++kc) {
      int g = kc >> 1;
      f16x8 af = __builtin_bit_cast(f16x8, *(const uint4*)(xtb +
          ((size_t)(g * HW + p0 + wv * 16 + n16)) * 128 + (kc & 1) * 64 + q * 16));
      #pragma unroll
      for (int nt = 0; nt < 5; ++nt) {
        f16x8 bfo = __builtin_bit_cast(f16x8, *(const uint4*)(wfrag2 + (size_t)(((kc * 5 + nt) << 6) + lane) * 8));
        oacc[nt] = __builtin_amdgcn_mfma_f32_16x16x32_f16(af, bfo, oacc[nt], 0, 0, 0);
      }
    }
    #pragma unroll
    for (int nt = 0; nt < 5; ++nt) {
      int oc = nt * 16 + n16;
      if (oc < OFFC) {
        #pragma unroll
        for (int r = 0; r < 4; ++r)
          offl[(wv * 16 + q * 4 + r) * 74 + oc] = oacc[nt][r];
      }
    }
  }
  #pragma unroll
  for (int j = 0; j < 2; ++j)                   // B(gt=0, hh=0) for slice wv
    bf0[j] = *(const uint4*)(wfrag + ((size_t)(wv * 2 + j) * 64 + lane) * 8);
  __syncthreads();                              // offl ready

  auto issue = [&](int gt, uint4* dd, u32* wpp) {
    int pxl = sp * 16 + n16;
    float oy = offl[pxl * 74 + gt * 2];
    float ox = offl[pxl * 74 + gt * 2 + 1];
    int g = (gt * 57) >> 9;                     // gt/9
    int t = gt - g * 9;
    int i = (t * 683) >> 11;                    // t/3
    int j = t - i * 3;
    int ob[4];
    mkpre(fh + (float)(i - 1) + oy, fxp + (float)(j - 1) + ox, ob, wpp);
    const char* xg = xtb + (size_t)g * HW * 128;
    #pragma unroll
    for (int c = 0; c < 4; ++c)
      dd[c] = *(const uint4*)(xg + ob[c] + chb);
  };
  auto produce = [&](int slot, const uint4* dd, const u32* wpp) {
    *(uint4*)&astage[(slot * 8 + sp * 2 + hp) * 512 + lane * 8] = bil16(dd, wpp);
  };

  // ---- pipeline prologue: fill buf0, issue gt=1 ----
  issue(0, d[0], wp[0]);
  issue(1, d[1], wp[1]);
  produce(0, d[0], wp[0]);
  __syncthreads();                              // buf0 ready

  // ---- main loop: one barrier per gt ----
  #pragma unroll 1
  for (int gt = 0; gt < 36; ++gt) {
    int slot = gt & 1;
    if (gt < 35) {
      int s = (gt + 1) & 1;
      produce(s, d[s], wp[s]);                  // bilerp gt+1 -> other buffer
      if (gt + 2 < 36) issue(gt + 2, d[slot], wp[slot]);
    }
    // transient hh=1 B-frags (L2-hot)
    uint4 bf1[2];
    const u16* wb1 = wfrag + ((size_t)((2 * gt + 1) * 16 + wv * 2) * 64 + lane) * 8;
    bf1[0] = *(const uint4*)(wb1);
    bf1[1] = *(const uint4*)(wb1 + 512);
    #pragma unroll
    for (int mt = 0; mt < 4; ++mt) {
      f16x8 af = __builtin_bit_cast(f16x8,
          *(const uint4*)&astage[(slot * 8 + mt * 2 + 0) * 512 + lane * 8]);
      acc[mt][0] = __builtin_amdgcn_mfma_f32_16x16x32_f16(af, __builtin_bit_cast(f16x8, bf0[0]), acc[mt][0], 0, 0, 0);
      acc[mt][1] = __builtin_amdgcn_mfma_f32_16x16x32_f16(af, __builtin_bit_cast(f16x8, bf0[1]), acc[mt][1], 0, 0, 0);
    }
    #pragma unroll
    for (int mt = 0; mt < 4; ++mt) {
      f16x8 af = __builtin_bit_cast(f16x8,
          *(const uint4*)&astage[(slot * 8 + mt * 2 + 1) * 512 + lane * 8]);
      acc[mt][0] = __builtin_amdgcn_mfma_f32_16x16x32_f16(af, __builtin_bit_cast(f16x8, bf1[0]), acc[mt][0], 0, 0, 0);
      acc[mt][1] = __builtin_amdgcn_mfma_f32_16x16x32_f16(af, __builtin_bit_cast(f16x8, bf1[1]), acc[mt][1], 0, 0, 0);
    }
    if (gt < 35) {                              // prefetch hh=0 B of gt+1
      const u16* wb0 = wfrag + ((size_t)((2 * gt + 2) * 16 + wv * 2) * 64 + lane) * 8;
      bf0[0] = *(const uint4*)(wb0);
      bf0[1] = *(const uint4*)(wb0 + 512);
    }
    __syncthreads();
  }

  // ---- epilogue: px = p0+mt*16+q*4+r, cout = wv*32 + j*16 + n16; ReLU ----
  float* op = out + (size_t)b * COUT * HW + p0;
  #pragma unroll
  for (int mt = 0; mt < 4; ++mt)
    #pragma unroll
    for (int j = 0; j < 2; ++j) {
      f32x4 v = acc[mt][j];
      #pragma unroll
      for (int r = 0; r < 4; ++r) v[r] = fmaxf(v[r], 0.f);
      int cout = wv * 32 + j * 16 + n16;
      *(f32x4*)(op + (size_t)cout * HW + mt * 16 + q * 4) = v;
    }
}

// ---------------------------------------------------------------------------
extern "C" void kernel_launch(void* const* d_in, const int* in_sizes, int n_in,
                              void* d_out, int out_size, void* d_ws, size_t ws_size,
                              hipStream_t stream) {
  const float* x  = (const float*)d_in[0];
  const float* wo = (const float*)d_in[1];
  const float* bo = (const float*)d_in[2];
  const float* wd = (const float*)d_in[3];
  float* out = (float*)d_out;

  // ws: xt 16,777,216 | wfrag 1,179,648 | wfrag2 40,960
  u16* xtp    = (u16*)d_ws;
  u16* wfrag  = (u16*)((char*)d_ws + 16777216);
  u16* wfrag2 = (u16*)((char*)d_ws + 16777216 + 1179648);

  kprep<<<1232, 256, 0, stream>>>(x, wd, wo, xtp, wfrag, wfrag2);
  k2   <<<512,  512, 0, stream>>>(xtp, wfrag2, bo, wfrag, out);
}

// Round 9
// 181.952 us; speedup vs baseline: 1.8465x; 1.6665x over previous
//
#include <hip/hip_runtime.h>
#include <stdint.h>

// B=2, CIN=256, COUT=256, H=W=128, K=3, G=4
#define HW    16384
#define CIN   256
#define COUT  256
#define Hh    128
#define Ww    128
#define OFFC  72        // G*2*K*K

typedef __attribute__((ext_vector_type(4))) float    f32x4;
typedef __attribute__((ext_vector_type(2))) _Float16 f16x2;
typedef __attribute__((ext_vector_type(8))) _Float16 f16x8;
typedef unsigned short u16;
typedef unsigned int   u32;

__device__ __forceinline__ u16 f2h(float f) { return __builtin_bit_cast(u16, (_Float16)f); }
__device__ __forceinline__ u32 pk2(float f) { u32 h = f2h(f); return h | (h << 16); }
__device__ __forceinline__ f16x2 bch(u32 u) { return __builtin_bit_cast(f16x2, u); }

// ---------------------------------------------------------------------------
// KPREP: {x f32 NCHW -> xt f16 [b*4+g][px][64]} (128-px tiles) + {w_deform ->
// wfrag f16 [kc72][nt16][lane64][j8]} + {w_offset -> wfrag2 f16}
// ---------------------------------------------------------------------------
__global__ __launch_bounds__(256) void kprep(const float* __restrict__ x, const float* __restrict__ wd,
                                             const float* __restrict__ wo, u16* __restrict__ xt,
                                             u16* __restrict__ wfrag, u16* __restrict__ wfrag2) {
  __shared__ float smem[64 * 129];              // 33 KB
  int blk = blockIdx.x;
  if (blk < 1024) {                             // ---- transpose to NHWC f16, 128 px ----
    int bg = blk >> 7;
    int p0 = (blk & 127) << 7;
    const float* src = x + (size_t)bg * 64 * HW + p0;
    #pragma unroll
    for (int r = 0; r < 8; ++r) {
      int idx = (threadIdx.x + 256 * r) * 4;    // 0..8191
      int c = idx >> 7, px = idx & 127;
      f32x4 v = *(const f32x4*)(src + (size_t)c * HW + px);
      smem[c * 129 + px + 0] = v[0];
      smem[c * 129 + px + 1] = v[1];
      smem[c * 129 + px + 2] = v[2];
      smem[c * 129 + px + 3] = v[3];
    }
    __syncthreads();
    int px = threadIdx.x >> 1, seg = threadIdx.x & 1;   // seg = 32-ch half
    u32 w[16];
    #pragma unroll
    for (int k = 0; k < 16; ++k) {
      float lo = smem[(seg * 32 + 2 * k) * 129 + px];
      float hi = smem[(seg * 32 + 2 * k + 1) * 129 + px];
      w[k] = (u32)f2h(lo) | ((u32)f2h(hi) << 16);
    }
    u16* dst = xt + ((size_t)bg * HW + p0 + px) * 64 + seg * 32;
    *(uint4*)(dst + 0)  = make_uint4(w[0],  w[1],  w[2],  w[3]);
    *(uint4*)(dst + 8)  = make_uint4(w[4],  w[5],  w[6],  w[7]);
    *(uint4*)(dst + 16) = make_uint4(w[8],  w[9],  w[10], w[11]);
    *(uint4*)(dst + 24) = make_uint4(w[12], w[13], w[14], w[15]);
  } else if (blk < 1152) {                      // ---- w_deform prepack (8 couts) ----
    int bb = blk - 1024;                        // 0..127
    int nh = bb & 31;                           // couts [nh*8, nh*8+8)
    int g  = bb >> 5;
    const float* src = wd + (size_t)(nh * 8) * 2304 + (size_t)g * 64 * 9;
    #pragma unroll
    for (int r = 0; r < 18; ++r) {
      int idx = threadIdx.x + 256 * r;          // 0..4607
      int cl  = idx / 576;
      int rem = idx - cl * 576;
      smem[cl * 576 + rem] = src[(size_t)cl * 2304 + rem];
    }
    __syncthreads();
    int nt = nh >> 1, nb = (nh & 1) * 8;
    #pragma unroll
    for (int r = 0; r < 18; ++r) {
      int o  = threadIdx.x + 256 * r;           // 0..4607
      int j  = o & 7;
      int n8 = (o >> 3) & 7;
      int q  = (o >> 6) & 3;
      int kcl = o >> 8;                         // t*2+half
      int t = kcl >> 1, half = kcl & 1;
      int cg = half * 32 + q * 8 + j;
      float v = smem[n8 * 576 + cg * 9 + t];
      int kc = (g * 9 + t) * 2 + half;
      int lane = q * 16 + nb + n8;
      wfrag[((size_t)(kc * 16 + nt) * 64 + lane) * 8 + j] = f2h(v);
    }
  } else {                                      // ---- w_offset prepack ----
    int e = (blk - 1152) * 256 + threadIdx.x;   // < 20480
    int j = e & 7;
    int lane = (e >> 3) & 63;
    int idx = e >> 9;
    int kc = idx / 5, nt = idx - 5 * kc;
    int n16 = lane & 15, q = lane >> 4;
    int oc = nt * 16 + n16;
    int c  = kc * 32 + q * 8 + j;
    float v = (oc < OFFC) ? wo[(size_t)oc * CIN + c] : 0.f;
    wfrag2[e] = f2h(v);
  }
}

// ---------------------------------------------------------------------------
// K2: symmetric fused DCN. Block = 8 waves (512 thr), M=64 px, N=256.
//   Wave w PRODUCES A half-tile (subtile w>>1, 32-ch half w&1): 4 corner
//   dwordx4 gathers + pk-f16 bilerp -> LDS; CONSUMES all 8 half-tiles x
//   cout slice [w*32,w*32+32): acc[4][2]=32 acc-regs.
//   Main loop unrolled x2 with EXPLICIT ping-pong reg sets (dA/dB, wpA/wpB) --
//   R6-R8 used runtime-indexed local arrays (d[slot]) which the compiler
//   allocates to SCRATCH: 605 MB/launch scratch traffic (= 512blk x 512thr x
//   36gt x 64B exactly). All array indices here are compile-time.
// ---------------------------------------------------------------------------
__device__ __forceinline__ void mkpre(float yy, float xx, int* ob, u32* wp) {
  float y0f = floorf(yy), x0f = floorf(xx);
  float fy = yy - y0f, fx = xx - x0f;
  int y0 = (int)y0f, x0 = (int)x0f;
  int y1 = y0 + 1, x1 = x0 + 1;
  float vy0 = (y0 >= 0 && y0 < Hh) ? 1.f : 0.f;
  float vy1 = (y1 >= 0 && y1 < Hh) ? 1.f : 0.f;
  float vx0 = (x0 >= 0 && x0 < Ww) ? 1.f : 0.f;
  float vx1 = (x1 >= 0 && x1 < Ww) ? 1.f : 0.f;
  wp[0] = pk2((1.f - fy) * (1.f - fx) * vy0 * vx0);   // zero-pad folded into weights
  wp[1] = pk2((1.f - fy) * fx * vy0 * vx1);
  wp[2] = pk2(fy * (1.f - fx) * vy1 * vx0);
  wp[3] = pk2(fy * fx * vy1 * vx1);
  int cy0 = min(max(y0, 0), Hh - 1), cy1 = min(max(y1, 0), Hh - 1);
  int cx0 = min(max(x0, 0), Ww - 1), cx1 = min(max(x1, 0), Ww - 1);
  ob[0] = (cy0 * Ww + cx0) << 7;                // byte offsets, 128 B pixel records
  ob[1] = (cy0 * Ww + cx1) << 7;
  ob[2] = (cy1 * Ww + cx0) << 7;
  ob[3] = (cy1 * Ww + cx1) << 7;
}

__device__ __forceinline__ uint4 bil16(const uint4* v, const u32* wp) {
  f16x2 W0 = bch(wp[0]), W1 = bch(wp[1]), W2 = bch(wp[2]), W3 = bch(wp[3]);
  uint4 r;
  { f16x2 s = bch(v[0].x) * W0 + bch(v[1].x) * W1 + bch(v[2].x) * W2 + bch(v[3].x) * W3; r.x = __builtin_bit_cast(u32, s); }
  { f16x2 s = bch(v[0].y) * W0 + bch(v[1].y) * W1 + bch(v[2].y) * W2 + bch(v[3].y) * W3; r.y = __builtin_bit_cast(u32, s); }
  { f16x2 s = bch(v[0].z) * W0 + bch(v[1].z) * W1 + bch(v[2].z) * W2 + bch(v[3].z) * W3; r.z = __builtin_bit_cast(u32, s); }
  { f16x2 s = bch(v[0].w) * W0 + bch(v[1].w) * W1 + bch(v[2].w) * W2 + bch(v[3].w) * W3; r.w = __builtin_bit_cast(u32, s); }
  return r;
}

__global__ __launch_bounds__(512) void k2(const u16* __restrict__ xt, const u16* __restrict__ wfrag2,
                                          const float* __restrict__ bo, const u16* __restrict__ wfrag,
                                          float* __restrict__ out) {
  __shared__ u16   astage[2 * 8 * 512];         // [buf][s4][h2][lane][8] = 16 KB
  __shared__ float offl[64 * 74];               // [px][oc] stride-74, 18.5 KB
  int tid  = threadIdx.x;
  int lane = tid & 63, n16 = lane & 15, q = (tid >> 4) & 3;
  int wv   = tid >> 6;                          // 0..7
  int sp   = wv >> 1;                           // produced px subtile
  int hp   = wv & 1;                            // produced 32-ch half
  int b  = blockIdx.x >> 8;
  int p0 = (blockIdx.x & 255) << 6;
  int h  = p0 >> 7, w0 = p0 & 127;
  const char* xtb = (const char*)xt + (size_t)b * 4 * HW * 128;
  float fh  = (float)h;
  float fxp = (float)(w0 + sp * 16 + n16);      // producer-pixel x
  int   chb = hp * 64 + q * 16;                 // byte offset within 128 B record

  f32x4 acc[4][2];
  #pragma unroll
  for (int mt = 0; mt < 4; ++mt) {
    acc[mt][0] = (f32x4){0.f, 0.f, 0.f, 0.f};
    acc[mt][1] = (f32x4){0.f, 0.f, 0.f, 0.f};
  }

  // ---- phase 0: waves 0-3 compute offset conv -> offl ----
  if (wv < 4) {
    f32x4 oacc[5];
    #pragma unroll
    for (int nt = 0; nt < 5; ++nt) {
      int oc = nt * 16 + n16;
      float bv = (oc < OFFC) ? bo[oc] : 0.f;
      oacc[nt] = (f32x4){bv, bv, bv, bv};
    }
    #pragma unroll
    for (int kc = 0; kc < 8; ++kc) {
      int g = kc >> 1;
      f16x8 af = __builtin_bit_cast(f16x8, *(const uint4*)(xtb +
          ((size_t)(g * HW + p0 + wv * 16 + n16)) * 128 + (kc & 1) * 64 + q * 16));
      #pragma unroll
      for (int nt = 0; nt < 5; ++nt) {
        f16x8 bfo = __builtin_bit_cast(f16x8, *(const uint4*)(wfrag2 + (size_t)(((kc * 5 + nt) << 6) + lane) * 8));
        oacc[nt] = __builtin_amdgcn_mfma_f32_16x16x32_f16(af, bfo, oacc[nt], 0, 0, 0);
      }
    }
    #pragma unroll
    for (int nt = 0; nt < 5; ++nt) {
      int oc = nt * 16 + n16;
      if (oc < OFFC) {
        #pragma unroll
        for (int r = 0; r < 4; ++r)
          offl[(wv * 16 + q * 4 + r) * 74 + oc] = oacc[nt][r];
      }
    }
  }
  uint4 bf0[2];                                 // persistent hh=0 B-frags (slice wv)
  bf0[0] = *(const uint4*)(wfrag + ((size_t)(wv * 2 + 0) * 64 + lane) * 8);
  bf0[1] = *(const uint4*)(wfrag + ((size_t)(wv * 2 + 1) * 64 + lane) * 8);
  __syncthreads();                              // offl ready

  uint4 dA[4], dB[4];                           // ping-pong gather sets (const-indexed!)
  u32   wpA[4], wpB[4];

  auto issue = [&](int gt, uint4* dd, u32* wpp) {
    int pxl = sp * 16 + n16;
    float oy = offl[pxl * 74 + gt * 2];
    float ox = offl[pxl * 74 + gt * 2 + 1];
    int g = (gt * 57) >> 9;                     // gt/9
    int t = gt - g * 9;
    int i = (t * 683) >> 11;                    // t/3
    int j = t - i * 3;
    int ob[4];
    mkpre(fh + (float)(i - 1) + oy, fxp + (float)(j - 1) + ox, ob, wpp);
    const char* xg = xtb + (size_t)g * HW * 128;
    #pragma unroll
    for (int c = 0; c < 4; ++c)
      dd[c] = *(const uint4*)(xg + ob[c] + chb);
  };
  auto consume = [&](int slot, int gt) {        // slot passed as constant
    uint4 bf1[2];
    const u16* wb1 = wfrag + ((size_t)((2 * gt + 1) * 16 + wv * 2) * 64 + lane) * 8;
    bf1[0] = *(const uint4*)(wb1);
    bf1[1] = *(const uint4*)(wb1 + 512);
    #pragma unroll
    for (int mt = 0; mt < 4; ++mt) {
      f16x8 af = __builtin_bit_cast(f16x8,
          *(const uint4*)&astage[(slot * 8 + mt * 2 + 0) * 512 + lane * 8]);
      acc[mt][0] = __builtin_amdgcn_mfma_f32_16x16x32_f16(af, __builtin_bit_cast(f16x8, bf0[0]), acc[mt][0], 0, 0, 0);
      acc[mt][1] = __builtin_amdgcn_mfma_f32_16x16x32_f16(af, __builtin_bit_cast(f16x8, bf0[1]), acc[mt][1], 0, 0, 0);
    }
    #pragma unroll
    for (int mt = 0; mt < 4; ++mt) {
      f16x8 af = __builtin_bit_cast(f16x8,
          *(const uint4*)&astage[(slot * 8 + mt * 2 + 1) * 512 + lane * 8]);
      acc[mt][0] = __builtin_amdgcn_mfma_f32_16x16x32_f16(af, __builtin_bit_cast(f16x8, bf1[0]), acc[mt][0], 0, 0, 0);
      acc[mt][1] = __builtin_amdgcn_mfma_f32_16x16x32_f16(af, __builtin_bit_cast(f16x8, bf1[1]), acc[mt][1], 0, 0, 0);
    }
    if (gt < 35) {                              // prefetch hh=0 B of gt+1
      const u16* wb0 = wfrag + ((size_t)((2 * gt + 2) * 16 + wv * 2) * 64 + lane) * 8;
      bf0[0] = *(const uint4*)(wb0);
      bf0[1] = *(const uint4*)(wb0 + 512);
    }
  };

  // ---- prologue: gt=0 -> dA, gt=1 -> dB, produce slot0 from dA ----
  issue(0, dA, wpA);
  issue(1, dB, wpB);
  *(uint4*)&astage[(0 * 8 + sp * 2 + hp) * 512 + lane * 8] = bil16(dA, wpA);
  __syncthreads();                              // slot0 ready

  // ---- main loop, x2 unrolled: one barrier per gt, all indices constant ----
  #pragma unroll 1
  for (int gt = 0; gt < 36; gt += 2) {
    // even gt: consume slot0; produce gt+1 (dB) -> slot1; issue gt+2 -> dA
    *(uint4*)&astage[(1 * 8 + sp * 2 + hp) * 512 + lane * 8] = bil16(dB, wpB);
    if (gt + 2 < 36) issue(gt + 2, dA, wpA);
    consume(0, gt);
    __syncthreads();
    // odd gt+1: consume slot1; produce gt+2 (dA) -> slot0; issue gt+3 -> dB
    if (gt + 2 < 36) {
      *(uint4*)&astage[(0 * 8 + sp * 2 + hp) * 512 + lane * 8] = bil16(dA, wpA);
      issue(gt + 3, dB, wpB);                   // gt+3 == 36 never reached (gt<34 here)
    }
    consume(1, gt + 1);
    __syncthreads();
  }

  // ---- epilogue: px = p0+mt*16+q*4+r, cout = wv*32 + j*16 + n16; ReLU ----
  float* op = out + (size_t)b * COUT * HW + p0;
  #pragma unroll
  for (int mt = 0; mt < 4; ++mt)
    #pragma unroll
    for (int j = 0; j < 2; ++j) {
      f32x4 v = acc[mt][j];
      #pragma unroll
      for (int r = 0; r < 4; ++r) v[r] = fmaxf(v[r], 0.f);
      int cout = wv * 32 + j * 16 + n16;
      *(f32x4*)(op + (size_t)cout * HW + mt * 16 + q * 4) = v;
    }
}

// ---------------------------------------------------------------------------
extern "C" void kernel_launch(void* const* d_in, const int* in_sizes, int n_in,
                              void* d_out, int out_size, void* d_ws, size_t ws_size,
                              hipStream_t stream) {
  const float* x  = (const float*)d_in[0];
  const float* wo = (const float*)d_in[1];
  const float* bo = (const float*)d_in[2];
  const float* wd = (const float*)d_in[3];
  float* out = (float*)d_out;

  // ws: xt 16,777,216 | wfrag 1,179,648 | wfrag2 40,960
  u16* xtp    = (u16*)d_ws;
  u16* wfrag  = (u16*)((char*)d_ws + 16777216);
  u16* wfrag2 = (u16*)((char*)d_ws + 16777216 + 1179648);

  kprep<<<1232, 256, 0, stream>>>(x, wd, wo, xtp, wfrag, wfrag2);
  k2   <<<512,  512, 0, stream>>>(xtp, wfrag2, bo, wfrag, out);
}